// Round 1
// baseline (3412.328 us; speedup 1.0000x reference)
//
#include <hip/hip_runtime.h>
#include <hip/hip_cooperative_groups.h>
#include <cstdint>

namespace cg = cooperative_groups;

typedef unsigned short u16;
typedef __attribute__((ext_vector_type(8))) short bf16x8;
typedef __attribute__((ext_vector_type(4))) float f32x4;

#define DI __device__ __forceinline__

// ---- problem constants ----
constexpr int VV = 10000, E = 512, H = 512, NH = 8, HD = 64;
constexpr int B = 32, T = 128, S = 512, T1 = 129;
constexpr int G4 = 2048;          // 4*H
constexpr int M_ROWS = T1 * B;    // 4128

DI u16 f2bf(float f) {
  uint32_t u = __builtin_bit_cast(uint32_t, f);
  u = (u + 0x7FFF + ((u >> 16) & 1)) >> 16;
  return (u16)u;
}
DI float sigm(float x) { return 1.f / (1.f + __expf(-x)); }
DI float tanh_(float x) { return 1.f - 2.f / (__expf(2.f * x) + 1.f); }  // NaN-free form

DI f32x4 MFMA(bf16x8 a, bf16x8 b, f32x4 c) {
  return __builtin_amdgcn_mfma_f32_16x16x32_bf16(a, b, c, 0, 0, 0);
}

#define GLD_LDS(gptr, lptr)                                                     \
  __builtin_amdgcn_global_load_lds(                                             \
      (const __attribute__((address_space(1))) uint32_t*)(const void*)(gptr),   \
      (__attribute__((address_space(3))) uint32_t*)(void*)(lptr), 16, 0, 0)

// ================= convert f32 -> bf16 (flat, n % 4 == 0) =================
__global__ __launch_bounds__(256) void k_convert(const float* __restrict__ src,
                                                 u16* __restrict__ dst, int n4) {
  int i = blockIdx.x * 256 + threadIdx.x;
  int stride = gridDim.x * 256;
  for (; i < n4; i += stride) {
    float4 v = ((const float4*)src)[i];
    ushort4 o;
    o.x = f2bf(v.x); o.y = f2bf(v.y); o.z = f2bf(v.z); o.w = f2bf(v.w);
    ((ushort4*)dst)[i] = o;
  }
}

// ================= embedding gather (+SOS prepend) -> bf16 [T1][B][E] =================
__global__ __launch_bounds__(256) void k_embed(const int* __restrict__ toks,
                                               const float* __restrict__ emb,
                                               u16* __restrict__ out) {
  int idx = blockIdx.x * 256 + threadIdx.x;  // one float4 chunk
  int total = T1 * B * (E / 4);
  if (idx >= total) return;
  int ch = idx & (E / 4 - 1);
  int r = idx / (E / 4);
  int t = r >> 5, b = r & 31;
  int tok = (t == 0) ? 1 : toks[b * T + (t - 1)];
  float4 v = ((const float4*)(emb + (size_t)tok * E))[ch];
  ushort4 o;
  o.x = f2bf(v.x); o.y = f2bf(v.y); o.z = f2bf(v.z); o.w = f2bf(v.w);
  ((ushort4*)out)[idx] = o;
}

// ================= generic NT GEMM, bf16 in, fp32 acc =================
// C[r][c] = sum_k A[r][k]*Bm[c][k],  K == 512 fixed, lds swizzled stage via global_load_lds.
// MODE 0: fp32 gate layout [T1][2048][B] + bias + bias2
// MODE 1: bf16 [M][N] (+bias optional)
// MODE 2: Q layout bf16 [B][NH][T1][HD], (v+bias)*scale
// MODE 3: Vt layout bf16 [B][NH][HD][S], v+bias
// MODE 4: logits fp32, row remap (t,b)->(b,t): d_out[(b*129+t)*10000 + c]
template <int MODE>
__global__ __launch_bounds__(256) void k_gemm(const u16* __restrict__ A,
                                              const u16* __restrict__ Bm,
                                              const float* __restrict__ bias,
                                              const float* __restrict__ bias2,
                                              void* __restrict__ Cout, int M, int N,
                                              float scale) {
  __shared__ __align__(16) u16 As[128 * 64];
  __shared__ __align__(16) u16 Bs[128 * 64];
  const int tid = threadIdx.x, lane = tid & 63, wid = tid >> 6;
  const int wm = wid >> 1, wn = wid & 1;
  const int r0 = blockIdx.y * 128, n0 = blockIdx.x * 128;
  f32x4 acc[4][4] = {};
  const int brow = wid * 32;  // this wave stages rows [brow, brow+32) of both tiles

  for (int k0 = 0; k0 < 512; k0 += 64) {
    for (int q = 0; q < 4; q++) {
      int row_l = brow + q * 8 + (lane >> 3);
      int slot = lane & 7;
      int scol = (slot ^ (row_l & 7)) * 8;  // pre-swizzled source (rule #21)
      int ra = r0 + row_l; if (ra > M - 1) ra = M - 1;
      GLD_LDS(A + (size_t)ra * 512 + k0 + scol, &As[(brow + q * 8) * 64]);
      int rb = n0 + row_l; if (rb > N - 1) rb = N - 1;
      GLD_LDS(Bm + (size_t)rb * 512 + k0 + scol, &Bs[(brow + q * 8) * 64]);
    }
    __syncthreads();
    for (int ks = 0; ks < 2; ks++) {
      bf16x8 af[4], bf[4];
      for (int mt = 0; mt < 4; mt++) {
        int row = wm * 64 + mt * 16 + (lane & 15);
        int slot = (ks * 4 + (lane >> 4)) ^ (row & 7);
        af[mt] = *(const bf16x8*)&As[row * 64 + slot * 8];
      }
      for (int nt = 0; nt < 4; nt++) {
        int row = wn * 64 + nt * 16 + (lane & 15);
        int slot = (ks * 4 + (lane >> 4)) ^ (row & 7);
        bf[nt] = *(const bf16x8*)&Bs[row * 64 + slot * 8];
      }
      for (int mt = 0; mt < 4; mt++)
        for (int nt = 0; nt < 4; nt++)
          acc[mt][nt] = MFMA(af[mt], bf[nt], acc[mt][nt]);
    }
    __syncthreads();
  }

  for (int mt = 0; mt < 4; mt++)
    for (int nt = 0; nt < 4; nt++) {
      int c = n0 + wn * 64 + nt * 16 + (lane & 15);
      float bv = 0.f;
      if (c < N) {
        if (bias) bv += bias[c];
        if (bias2) bv += bias2[c];
      }
      for (int rg = 0; rg < 4; rg++) {
        int r = r0 + wm * 64 + mt * 16 + (lane >> 4) * 4 + rg;
        if (r >= M || c >= N) continue;
        float v = acc[mt][nt][rg];
        if constexpr (MODE == 0) {
          int t = r >> 5, b = r & 31;
          ((float*)Cout)[((size_t)t * G4 + c) * 32 + b] = v + bv;
        } else if constexpr (MODE == 1) {
          ((u16*)Cout)[(size_t)r * N + c] = f2bf(v + bv);
        } else if constexpr (MODE == 2) {
          int t = r >> 5, b = r & 31, h = c >> 6, d = c & 63;
          ((u16*)Cout)[((size_t)(b * NH + h) * T1 + t) * HD + d] = f2bf((v + bv) * scale);
        } else if constexpr (MODE == 3) {
          int b = r >> 9, s = r & 511, h = c >> 6, d = c & 63;
          ((u16*)Cout)[((size_t)(b * NH + h) * HD + d) * S + s] = f2bf(v + bv);
        } else {
          int t = r >> 5, b = r & 31;
          ((float*)Cout)[((size_t)b * T1 + t) * VV + c] = v;
        }
      }
    }
}

// ================= cooperative LSTM layer =================
// G: fp32 [T1][2048][32] precomputed x@Wih.T + bih + bhh
// Whh: bf16 [2048][512]; seq_out: bf16 [T1][B][512]; hbuf: bf16 [2][32][512]
// 32 WGs x 256 thr. WG owns 16 h-units; wave g = gate g. Whh frags persistent in VGPRs.
__global__ __launch_bounds__(256) void k_lstm(const float* __restrict__ G,
                                              const u16* __restrict__ Whh,
                                              u16* __restrict__ seq_out,
                                              u16* __restrict__ hbuf) {
  cg::grid_group grid = cg::this_grid();
  __shared__ __align__(16) u16 h_lds[32 * 512];       // 32KB, swizzled
  __shared__ float xchg[4][32][17];                   // gate dots, padded
  __shared__ __align__(16) u16 hx[32][16];            // transpose staging
  const int tid = threadIdx.x, lane = tid & 63, g = tid >> 6;
  const int u0 = blockIdx.x * 16;

  bf16x8 af[16];  // persistent Whh fragments: 64 VGPRs
  {
    int row = g * 512 + u0 + (lane & 15);
    const u16* wp = Whh + (size_t)row * 512 + (lane >> 4) * 8;
    for (int ks = 0; ks < 16; ks++) af[ks] = *(const bf16x8*)(wp + ks * 32);
  }
  float cst[2] = {0.f, 0.f};

  for (int t = 0; t < T1; t++) {
    // ---- stage h into LDS (swizzled) ----
    if (t == 0) {
      uint4 z = {0, 0, 0, 0};
      for (int j = 0; j < 8; j++) *(uint4*)&h_lds[(tid + 256 * j) * 8] = z;
    } else {
      const u16* hsrc = hbuf + (size_t)(t & 1) * (32 * 512);
      for (int j = 0; j < 8; j++) {
        int cid = tid + 256 * j;
        int row = cid >> 6, slot = cid & 63;
        uint4 v = *(const uint4*)&hsrc[row * 512 + slot * 8];
        *(uint4*)&h_lds[row * 512 + ((slot ^ (row & 7)) * 8)] = v;
      }
    }
    __syncthreads();

    // ---- recurrent dots: wave g computes gate g for its 16 units x 32 batches ----
    f32x4 acc[2] = {};
    for (int ks = 0; ks < 16; ks++) {
      for (int nt = 0; nt < 2; nt++) {
        int row = nt * 16 + (lane & 15);
        bf16x8 bfv = *(const bf16x8*)&h_lds[row * 512 + (((ks * 4 + (lane >> 4)) ^ (row & 7)) * 8)];
        acc[nt] = MFMA(af[ks], bfv, acc[nt]);
      }
    }
    for (int nt = 0; nt < 2; nt++)
      for (int rg = 0; rg < 4; rg++) {
        int b = nt * 16 + (lane & 15);
        int u = (lane >> 4) * 4 + rg;
        xchg[g][b][u] = acc[nt][rg];
      }
    __syncthreads();

    // ---- combine gates, update c (registers), produce h ----
    for (int j = 0; j < 2; j++) {
      int p = tid + 256 * j;
      int b = p & 31, u = p >> 5;
      const float* Gp = G + ((size_t)t * G4 + u0 + u) * 32 + b;
      float i_ = sigm(xchg[0][b][u] + Gp[0]);
      float f_ = sigm(xchg[1][b][u] + Gp[512 * 32]);
      float g_ = tanh_(xchg[2][b][u] + Gp[1024 * 32]);
      float o_ = sigm(xchg[3][b][u] + Gp[1536 * 32]);
      float c = f_ * cst[j] + i_ * g_;
      cst[j] = c;
      hx[b][u] = f2bf(o_ * tanh_(c));
    }
    __syncthreads();

    // ---- repack + store h (coalesced-ish 32B rows) ----
    if (tid < 32) {
      uint4 v0 = *(const uint4*)&hx[tid][0];
      uint4 v1 = *(const uint4*)&hx[tid][8];
      u16* hd = hbuf + (size_t)((t + 1) & 1) * (32 * 512) + (size_t)tid * 512 + u0;
      *(uint4*)hd = v0; *(uint4*)(hd + 8) = v1;
      u16* sd = seq_out + ((size_t)t * 32 + tid) * 512 + u0;
      *(uint4*)sd = v0; *(uint4*)(sd + 8) = v1;
    }
    __threadfence();
    grid.sync();
  }
}

// ================= attention: one WG per (b, head, t-tile of 32) =================
// Q bf16 [B][NH][T1][HD] (pre-scaled), K bf16 [B*S][H] (cols h*64+d), Vt bf16 [B][NH][HD][S]
// ctx bf16 [T1][B][H]
__global__ __launch_bounds__(256) void k_attn(const u16* __restrict__ Q,
                                              const u16* __restrict__ Kall,
                                              const u16* __restrict__ Vt,
                                              u16* __restrict__ ctx) {
  __shared__ __align__(16) u16 p_lds[32 * 520];
  __shared__ float red[4][32], red2[4][32], rsum[32];
  const int bid = blockIdx.x;
  const int tt = bid % 5, h = (bid / 5) & 7, b = bid / 40;
  const int tid = threadIdx.x, lane = tid & 63, w = tid >> 6;

  bf16x8 qf[2][2];
  for (int mt = 0; mt < 2; mt++)
    for (int ks = 0; ks < 2; ks++) {
      int t = tt * 32 + mt * 16 + (lane & 15);
      if (t > 128) t = 128;
      qf[mt][ks] = *(const bf16x8*)&Q[((size_t)(b * NH + h) * T1 + t) * HD + ks * 32 + (lane >> 4) * 8];
    }

  // scores in registers: wave w covers s-blocks nt = w + 4j
  f32x4 sc[8][2] = {};
  for (int j = 0; j < 8; j++) {
    int nt = w + 4 * j;
    for (int ks = 0; ks < 2; ks++) {
      int srow = nt * 16 + (lane & 15);
      bf16x8 kf = *(const bf16x8*)&Kall[(size_t)(b * S + srow) * H + h * HD + ks * 32 + (lane >> 4) * 8];
      for (int mt = 0; mt < 2; mt++) sc[j][mt] = MFMA(qf[mt][ks], kf, sc[j][mt]);
    }
  }
  // per-row max within wave (rows: mt*16 + 4*(lane>>4) + rg ; 16-lane groups share a row)
  float rowm[2][4], rows_[2][4];
  for (int mt = 0; mt < 2; mt++)
    for (int rg = 0; rg < 4; rg++) {
      float m = -1e30f;
      for (int j = 0; j < 8; j++) m = fmaxf(m, sc[j][mt][rg]);
      for (int mk = 1; mk < 16; mk <<= 1) m = fmaxf(m, __shfl_xor(m, mk));
      rowm[mt][rg] = m;
      if ((lane & 15) == 0) red[w][mt * 16 + (lane >> 4) * 4 + rg] = m;
    }
  __syncthreads();
  for (int mt = 0; mt < 2; mt++)
    for (int rg = 0; rg < 4; rg++) {
      int row = mt * 16 + (lane >> 4) * 4 + rg;
      float M = fmaxf(fmaxf(red[0][row], red[1][row]), fmaxf(red[2][row], red[3][row]));
      float s = 0.f;
      for (int j = 0; j < 8; j++) {
        float p = __expf(sc[j][mt][rg] - M);
        s += p;
        p_lds[row * 520 + (w + 4 * j) * 16 + (lane & 15)] = f2bf(p);
      }
      for (int mk = 1; mk < 16; mk <<= 1) s += __shfl_xor(s, mk);
      rows_[mt][rg] = s;
      if ((lane & 15) == 0) red2[w][row] = s;
    }
  (void)rowm; (void)rows_;
  __syncthreads();
  if (tid < 32) rsum[tid] = red2[0][tid] + red2[1][tid] + red2[2][tid] + red2[3][tid];

  // PV: wave w handles d-block nt = w
  f32x4 pacc[2] = {};
  {
    int nt = w;
    for (int ks = 0; ks < 16; ks++) {
      bf16x8 vf = *(const bf16x8*)&Vt[((size_t)(b * NH + h) * HD + nt * 16 + (lane & 15)) * S + ks * 32 + (lane >> 4) * 8];
      for (int mt = 0; mt < 2; mt++) {
        bf16x8 pf = *(const bf16x8*)&p_lds[(mt * 16 + (lane & 15)) * 520 + ks * 32 + (lane >> 4) * 8];
        pacc[mt] = MFMA(pf, vf, pacc[mt]);
      }
    }
  }
  __syncthreads();
  for (int mt = 0; mt < 2; mt++)
    for (int rg = 0; rg < 4; rg++) {
      int lrow = mt * 16 + (lane >> 4) * 4 + rg;
      int trow = tt * 32 + lrow;
      if (trow < T1) {
        float v = pacc[mt][rg] / rsum[lrow];
        ctx[((size_t)trow * 32 + b) * H + h * HD + w * 16 + (lane & 15)] = f2bf(v);
      }
    }
}

// ================= in-place log_softmax over V per row =================
__global__ __launch_bounds__(256) void k_lsm(float* __restrict__ out) {
  float* p = out + (size_t)blockIdx.x * VV;
  const int tid = threadIdx.x;
  float m = -1e30f, s = 0.f;
  for (int i = tid; i < VV; i += 256) {
    float v = p[i];
    if (v > m) { s *= __expf(m - v); m = v; }
    s += __expf(v - m);
  }
  for (int off = 32; off; off >>= 1) {
    float m2 = __shfl_xor(m, off), s2 = __shfl_xor(s, off);
    float M = fmaxf(m, m2);
    s = s * __expf(m - M) + s2 * __expf(m2 - M);
    m = M;
  }
  __shared__ float wm[4], ws[4];
  if ((tid & 63) == 0) { wm[tid >> 6] = m; ws[tid >> 6] = s; }
  __syncthreads();
  float M = fmaxf(fmaxf(wm[0], wm[1]), fmaxf(wm[2], wm[3]));
  float Sv = ws[0] * __expf(wm[0] - M) + ws[1] * __expf(wm[1] - M) +
             ws[2] * __expf(wm[2] - M) + ws[3] * __expf(wm[3] - M);
  float lse = M + __logf(Sv);
  for (int i = tid; i < VV; i += 256) p[i] -= lse;
}

// ================= launch =================
extern "C" void kernel_launch(void* const* d_in, const int* in_sizes, int n_in,
                              void* d_out, int out_size, void* d_ws, size_t ws_size,
                              hipStream_t stream) {
  const int* inputs = (const int*)d_in[0];
  const float* enc = (const float*)d_in[1];
  const float* emb = (const float*)d_in[2];
  const float* Wih = (const float*)d_in[3];
  const float* Whh = (const float*)d_in[4];
  const float* bih = (const float*)d_in[5];
  const float* bhh = (const float*)d_in[6];
  const float* ipw = (const float*)d_in[7];
  const float* ipb = (const float*)d_in[8];
  const float* outw = (const float*)d_in[9];
  const float* outb = (const float*)d_in[10];
  const float* projw = (const float*)d_in[11];
  const float* genw = (const float*)d_in[12];
  float* out = (float*)d_out;

  char* wp = (char*)d_ws;
  auto alloc = [&](size_t bytes) {
    char* p = wp;
    wp += (bytes + 255) & ~(size_t)255;
    return p;
  };
  u16* embx = (u16*)alloc((size_t)M_ROWS * E * 2);        // 4.2MB
  u16* seq0 = (u16*)alloc((size_t)M_ROWS * H * 2);
  u16* seq1 = (u16*)alloc((size_t)M_ROWS * H * 2);
  u16* WihB = (u16*)alloc((size_t)2 * G4 * E * 2);
  u16* WhhB = (u16*)alloc((size_t)2 * G4 * H * 2);
  u16* ipwB = (u16*)alloc((size_t)3 * H * H * 2);
  u16* outwB = (u16*)alloc((size_t)H * H * 2);
  u16* projwB = (u16*)alloc((size_t)H * H * 2);
  u16* genwB = (u16*)alloc((size_t)VV * H * 2);           // 10.2MB
  u16* encB = (u16*)alloc((size_t)B * S * H * 2);         // 16.8MB
  u16* hbuf = (u16*)alloc((size_t)2 * 32 * 512 * 2);
  float* Gbuf = (float*)alloc((size_t)T1 * G4 * 32 * 4);  // 33.8MB
  u16* Qb = (u16*)alloc((size_t)B * NH * T1 * HD * 2);
  u16* ctxb = (u16*)alloc((size_t)M_ROWS * H * 2);
  // overlays (lifetimes disjoint):
  u16* Kall = (u16*)Gbuf;                                  // after LSTM done
  u16* Vtb = (u16*)((char*)Gbuf + (size_t)B * S * H * 2);
  u16* attout = encB;                                      // enc_bf16 dead after K/V GEMMs
  u16* hidden = (u16*)((char*)encB + (size_t)M_ROWS * H * 2);

  // ---- converts ----
  k_convert<<<1024, 256, 0, stream>>>(Wih, WihB, 2 * G4 * E / 4);
  k_convert<<<1024, 256, 0, stream>>>(Whh, WhhB, 2 * G4 * H / 4);
  k_convert<<<1024, 256, 0, stream>>>(ipw, ipwB, 3 * H * H / 4);
  k_convert<<<1024, 256, 0, stream>>>(outw, outwB, H * H / 4);
  k_convert<<<1024, 256, 0, stream>>>(projw, projwB, H * H / 4);
  k_convert<<<1024, 256, 0, stream>>>(genw, genwB, VV * H / 4);
  k_convert<<<1024, 256, 0, stream>>>(enc, encB, B * S * H / 4);
  k_embed<<<(M_ROWS * (E / 4) + 255) / 256, 256, 0, stream>>>(inputs, emb, embx);

  // ---- LSTM layer 0 ----
  k_gemm<0><<<dim3(16, 33), 256, 0, stream>>>(embx, WihB, bih, bhh, Gbuf, M_ROWS, G4, 1.f);
  {
    const float* gp = Gbuf; const u16* whp = WhhB; u16* so = seq0; u16* hb = hbuf;
    void* args[] = {&gp, &whp, &so, &hb};
    hipLaunchCooperativeKernel((void*)k_lstm, dim3(32), dim3(256), args, 0, stream);
  }
  // ---- LSTM layer 1 ----
  k_gemm<0><<<dim3(16, 33), 256, 0, stream>>>(seq0, WihB + (size_t)G4 * E, bih + G4, bhh + G4,
                                              Gbuf, M_ROWS, G4, 1.f);
  {
    const float* gp = Gbuf; const u16* whp = WhhB + (size_t)G4 * H; u16* so = seq1; u16* hb = hbuf;
    void* args[] = {&gp, &whp, &so, &hb};
    hipLaunchCooperativeKernel((void*)k_lstm, dim3(32), dim3(256), args, 0, stream);
  }

  // ---- attention projections (K/V overlay Gbuf — LSTM finished) ----
  k_gemm<1><<<dim3(4, 128), 256, 0, stream>>>(encB, ipwB + (size_t)H * H, ipb + H, nullptr,
                                              Kall, B * S, H, 1.f);
  k_gemm<3><<<dim3(4, 128), 256, 0, stream>>>(encB, ipwB + (size_t)2 * H * H, ipb + 2 * H, nullptr,
                                              Vtb, B * S, H, 1.f);
  k_gemm<2><<<dim3(4, 33), 256, 0, stream>>>(seq1, ipwB, ipb, nullptr, Qb, M_ROWS, H, 0.125f);

  k_attn<<<B * NH * 5, 256, 0, stream>>>(Qb, Kall, Vtb, ctxb);

  // ---- output projections ----
  k_gemm<1><<<dim3(4, 33), 256, 0, stream>>>(ctxb, outwB, outb, nullptr, attout, M_ROWS, H, 1.f);
  k_gemm<1><<<dim3(4, 33), 256, 0, stream>>>(attout, projwB, nullptr, nullptr, hidden, M_ROWS, H, 1.f);
  k_gemm<4><<<dim3(79, 33), 256, 0, stream>>>(hidden, genwB, nullptr, nullptr, out, M_ROWS, VV, 1.f);

  k_lsm<<<M_ROWS, 256, 0, stream>>>(out);

  (void)in_sizes; (void)n_in; (void)out_size; (void)ws_size;
}

// Round 2
// 2069.587 us; speedup vs baseline: 1.6488x; 1.6488x over previous
//
#include <hip/hip_runtime.h>
#include <cstdint>

typedef unsigned short u16;
typedef unsigned int u32;
typedef __attribute__((ext_vector_type(8))) short bf16x8;
typedef __attribute__((ext_vector_type(4))) float f32x4;

#define DI __device__ __forceinline__

// ---- problem constants ----
constexpr int VV = 10000, E = 512, H = 512, NH = 8, HD = 64;
constexpr int B = 32, T = 128, S = 512, T1 = 129;
constexpr int G4 = 2048;          // 4*H
constexpr int M_ROWS = T1 * B;    // 4128
constexpr int NWG_LSTM = 64;      // 32 for layer0 + 32 for layer1

DI u16 f2bf(float f) {
  uint32_t u = __builtin_bit_cast(uint32_t, f);
  u = (u + 0x7FFF + ((u >> 16) & 1)) >> 16;
  return (u16)u;
}
DI float sigm(float x) { return 1.f / (1.f + __expf(-x)); }
DI float tanh_(float x) { return 1.f - 2.f / (__expf(2.f * x) + 1.f); }  // NaN-free form

DI f32x4 MFMA(bf16x8 a, bf16x8 b, f32x4 c) {
  return __builtin_amdgcn_mfma_f32_16x16x32_bf16(a, b, c, 0, 0, 0);
}

#define GLD_LDS(gptr, lptr)                                                     \
  __builtin_amdgcn_global_load_lds(                                             \
      (const __attribute__((address_space(1))) uint32_t*)(const void*)(gptr),   \
      (__attribute__((address_space(3))) uint32_t*)(void*)(lptr), 16, 0, 0)

// ================= convert f32 -> bf16 (flat, n % 4 == 0) =================
__global__ __launch_bounds__(256) void k_convert(const float* __restrict__ src,
                                                 u16* __restrict__ dst, int n4) {
  int i = blockIdx.x * 256 + threadIdx.x;
  int stride = gridDim.x * 256;
  for (; i < n4; i += stride) {
    float4 v = ((const float4*)src)[i];
    ushort4 o;
    o.x = f2bf(v.x); o.y = f2bf(v.y); o.z = f2bf(v.z); o.w = f2bf(v.w);
    ((ushort4*)dst)[i] = o;
  }
}

// ================= embedding gather (+SOS prepend) -> bf16 [T1][B][E] =================
__global__ __launch_bounds__(256) void k_embed(const int* __restrict__ toks,
                                               const float* __restrict__ emb,
                                               u16* __restrict__ out) {
  int idx = blockIdx.x * 256 + threadIdx.x;  // one float4 chunk
  int total = T1 * B * (E / 4);
  if (idx >= total) return;
  int ch = idx & (E / 4 - 1);
  int r = idx / (E / 4);
  int t = r >> 5, b = r & 31;
  int tok = (t == 0) ? 1 : toks[b * T + (t - 1)];
  float4 v = ((const float4*)(emb + (size_t)tok * E))[ch];
  ushort4 o;
  o.x = f2bf(v.x); o.y = f2bf(v.y); o.z = f2bf(v.z); o.w = f2bf(v.w);
  ((ushort4*)out)[idx] = o;
}

// ================= generic NT GEMM, bf16 in, fp32 acc =================
// C[r][c] = sum_k A[r][k]*Bm[c][k],  K == 512 fixed.
// MODE 0: fp32 gate layout [T1][2048][B] + bias + bias2
// MODE 1: bf16 [M][N] (+bias optional)
// MODE 2: Q layout bf16 [B][NH][T1][HD], (v+bias)*scale
// MODE 3: Vt layout bf16 [B][NH][HD][S], v+bias
// MODE 4: logits fp32, row remap (t,b)->(b,t): d_out[(b*129+t)*10000 + c]
template <int MODE>
__global__ __launch_bounds__(256) void k_gemm(const u16* __restrict__ A,
                                              const u16* __restrict__ Bm,
                                              const float* __restrict__ bias,
                                              const float* __restrict__ bias2,
                                              void* __restrict__ Cout, int M, int N,
                                              float scale) {
  __shared__ __align__(16) u16 As[128 * 64];
  __shared__ __align__(16) u16 Bs[128 * 64];
  const int tid = threadIdx.x, lane = tid & 63, wid = tid >> 6;
  const int wm = wid >> 1, wn = wid & 1;
  const int r0 = blockIdx.y * 128, n0 = blockIdx.x * 128;
  f32x4 acc[4][4] = {};
  const int brow = wid * 32;  // this wave stages rows [brow, brow+32) of both tiles

  for (int k0 = 0; k0 < 512; k0 += 64) {
    for (int q = 0; q < 4; q++) {
      int row_l = brow + q * 8 + (lane >> 3);
      int slot = lane & 7;
      int scol = (slot ^ (row_l & 7)) * 8;  // pre-swizzled source (rule #21)
      int ra = r0 + row_l; if (ra > M - 1) ra = M - 1;
      GLD_LDS(A + (size_t)ra * 512 + k0 + scol, &As[(brow + q * 8) * 64]);
      int rb = n0 + row_l; if (rb > N - 1) rb = N - 1;
      GLD_LDS(Bm + (size_t)rb * 512 + k0 + scol, &Bs[(brow + q * 8) * 64]);
    }
    __syncthreads();
    for (int ks = 0; ks < 2; ks++) {
      bf16x8 af[4], bf[4];
      for (int mt = 0; mt < 4; mt++) {
        int row = wm * 64 + mt * 16 + (lane & 15);
        int slot = (ks * 4 + (lane >> 4)) ^ (row & 7);
        af[mt] = *(const bf16x8*)&As[row * 64 + slot * 8];
      }
      for (int nt = 0; nt < 4; nt++) {
        int row = wn * 64 + nt * 16 + (lane & 15);
        int slot = (ks * 4 + (lane >> 4)) ^ (row & 7);
        bf[nt] = *(const bf16x8*)&Bs[row * 64 + slot * 8];
      }
      for (int mt = 0; mt < 4; mt++)
        for (int nt = 0; nt < 4; nt++)
          acc[mt][nt] = MFMA(af[mt], bf[nt], acc[mt][nt]);
    }
    __syncthreads();
  }

  for (int mt = 0; mt < 4; mt++)
    for (int nt = 0; nt < 4; nt++) {
      int c = n0 + wn * 64 + nt * 16 + (lane & 15);
      float bv = 0.f;
      if (c < N) {
        if (bias) bv += bias[c];
        if (bias2) bv += bias2[c];
      }
      for (int rg = 0; rg < 4; rg++) {
        int r = r0 + wm * 64 + mt * 16 + (lane >> 4) * 4 + rg;
        if (r >= M || c >= N) continue;
        float v = acc[mt][nt][rg];
        if constexpr (MODE == 0) {
          int t = r >> 5, b = r & 31;
          ((float*)Cout)[((size_t)t * G4 + c) * 32 + b] = v + bv;
        } else if constexpr (MODE == 1) {
          ((u16*)Cout)[(size_t)r * N + c] = f2bf(v + bv);
        } else if constexpr (MODE == 2) {
          int t = r >> 5, b = r & 31, h = c >> 6, d = c & 63;
          ((u16*)Cout)[((size_t)(b * NH + h) * T1 + t) * HD + d] = f2bf((v + bv) * scale);
        } else if constexpr (MODE == 3) {
          int b = r >> 9, s = r & 511, h = c >> 6, d = c & 63;
          ((u16*)Cout)[((size_t)(b * NH + h) * HD + d) * S + s] = f2bf(v + bv);
        } else {
          int t = r >> 5, b = r & 31;
          ((float*)Cout)[((size_t)b * T1 + t) * VV + c] = v;
        }
      }
    }
}

// ================= fused 2-layer pipelined LSTM (cooperative, custom barrier) ======
// WG 0..31  = layer0 unit-slice wg*16,   reads precomputed G0 [T1][2048][32] fp32
// WG 32..63 = layer1 unit-slice (wg-32)*16, computes x-gates Wih1*h0 on the fly
// hbuf: [2][2][32][512] bf16 : hb0 ping-pong then hb1 ping-pong
// Step skew: at superstep u, L0 produces h0[u] (u<129), L1 produces h1[u-1] (u>=1).
__global__ __launch_bounds__(256) void k_lstm2(const float* __restrict__ G0,
                                               const u16* __restrict__ Whh0,
                                               const u16* __restrict__ Wih1,
                                               const u16* __restrict__ Whh1,
                                               const float* __restrict__ bih1,
                                               const float* __restrict__ bhh1,
                                               u16* __restrict__ seq1,
                                               u16* __restrict__ hbuf,
                                               u32* __restrict__ flags) {
  __shared__ __align__(16) u16 hA[32 * 512];   // recurrent h tile (overlaid by xchg/hx after MFMA)
  __shared__ __align__(16) u16 hX[32 * 512];   // L1 only: x = h0[u-1]
  float* xchg = (float*)hA;                    // [4][32][17] = 8704 B (after-MFMA overlay)
  u16* hx = (u16*)hA + 4352;                   // 1 KB transpose staging @ byte 8704
  const int tid = threadIdx.x, lane = tid & 63, g = tid >> 6;
  const int wg = blockIdx.x;
  const bool isL1 = wg >= 32;
  const int u0 = (isL1 ? wg - 32 : wg) * 16;

  u16* hb0 = hbuf;                  // [2][32][512]
  u16* hb1 = hbuf + 2 * 32 * 512;   // [2][32][512]

  // persistent weight fragments (A-operand), 64 VGPR each set
  bf16x8 afh[16], afx[16];
  {
    const u16* Wh = isL1 ? Whh1 : Whh0;
    int row = g * 512 + u0 + (lane & 15);
    const u16* wp = Wh + (size_t)row * 512 + (lane >> 4) * 8;
    for (int ks = 0; ks < 16; ks++) afh[ks] = *(const bf16x8*)(wp + ks * 32);
    if (isL1) {
      const u16* xp = Wih1 + (size_t)row * 512 + (lane >> 4) * 8;
      for (int ks = 0; ks < 16; ks++) afx[ks] = *(const bf16x8*)(xp + ks * 32);
    }
  }
  // L1 per-thread gate biases (bih1+bhh1) for its 2 (b,u)-points
  float bsum[2][4];
  if (isL1) {
    for (int j = 0; j < 2; j++) {
      int uu = (tid + 256 * j) >> 5;
      for (int gg = 0; gg < 4; gg++)
        bsum[j][gg] = bih1[gg * 512 + u0 + uu] + bhh1[gg * 512 + u0 + uu];
    }
  }
  float cst[2] = {0.f, 0.f};

  for (int u = 0; u < 130; u++) {
    const int t = isL1 ? (u - 1) : u;
    const bool active = isL1 ? (u >= 1) : (u < 129);

    if (active) {
      float gpre[2][4];
      if (!isL1) {
        // prefetch this step's G0 into regs (overlaps with h-stage latency)
        for (int j = 0; j < 2; j++) {
          int p = tid + 256 * j; int b = p & 31, uu = p >> 5;
          const float* Gp = G0 + ((size_t)t * G4 + u0 + uu) * 32 + b;
          gpre[j][0] = Gp[0];         gpre[j][1] = Gp[512 * 32];
          gpre[j][2] = Gp[1024 * 32]; gpre[j][3] = Gp[1536 * 32];
        }
      }
      // ---- stage h tiles into LDS (swizzled) ----
      {
        uint4 z = {0, 0, 0, 0};
        const u16* srcA = isL1 ? (hb1 + (size_t)(t & 1) * (32 * 512))
                               : (hb0 + (size_t)(t & 1) * (32 * 512));
        const u16* srcX = hb0 + (size_t)(u & 1) * (32 * 512);  // h0[u-1]
        for (int j = 0; j < 8; j++) {
          int cid = tid + 256 * j;
          int row = cid >> 6, slot = cid & 63;
          int dsto = row * 512 + ((slot ^ (row & 7)) * 8);
          if (t == 0) *(uint4*)&hA[dsto] = z;
          else        *(uint4*)&hA[dsto] = *(const uint4*)&srcA[row * 512 + slot * 8];
          if (isL1)   *(uint4*)&hX[dsto] = *(const uint4*)&srcX[row * 512 + slot * 8];
        }
      }
      __syncthreads();
      // ---- recurrent (+x) dots: wave g = gate g, 16 units x 32 batches ----
      f32x4 acc[2] = {};
      for (int ks = 0; ks < 16; ks++)
        for (int nt = 0; nt < 2; nt++) {
          int row = nt * 16 + (lane & 15);
          int off = row * 512 + (((ks * 4 + (lane >> 4)) ^ (row & 7)) * 8);
          acc[nt] = MFMA(afh[ks], *(const bf16x8*)&hA[off], acc[nt]);
          if (isL1) acc[nt] = MFMA(afx[ks], *(const bf16x8*)&hX[off], acc[nt]);
        }
      __syncthreads();  // all MFMA reads of hA done before xchg overlays it
      for (int nt = 0; nt < 2; nt++)
        for (int rg = 0; rg < 4; rg++)
          xchg[(g * 32 + nt * 16 + (lane & 15)) * 17 + (lane >> 4) * 4 + rg] = acc[nt][rg];
      __syncthreads();
      // ---- combine gates, update c (registers), produce h ----
      for (int j = 0; j < 2; j++) {
        int p = tid + 256 * j; int b = p & 31, uu = p >> 5;
        float gi, gf, gg_, go;
        if (!isL1) { gi = gpre[j][0]; gf = gpre[j][1]; gg_ = gpre[j][2]; go = gpre[j][3]; }
        else       { gi = bsum[j][0]; gf = bsum[j][1]; gg_ = bsum[j][2]; go = bsum[j][3]; }
        float i_ = sigm(xchg[(0 * 32 + b) * 17 + uu] + gi);
        float f_ = sigm(xchg[(1 * 32 + b) * 17 + uu] + gf);
        float g_ = tanh_(xchg[(2 * 32 + b) * 17 + uu] + gg_);
        float o_ = sigm(xchg[(3 * 32 + b) * 17 + uu] + go);
        float c = f_ * cst[j] + i_ * g_;
        cst[j] = c;
        hx[b * 16 + uu] = f2bf(o_ * tanh_(c));
      }
      __syncthreads();
      // ---- publish h (coalesced 32B rows per batch) ----
      if (tid < 32) {
        uint4 v0 = *(const uint4*)&hx[tid * 16];
        uint4 v1 = *(const uint4*)&hx[tid * 16 + 8];
        u16* hd = (isL1 ? hb1 : hb0) + (size_t)((t + 1) & 1) * (32 * 512) + (size_t)tid * 512 + u0;
        *(uint4*)hd = v0; *(uint4*)(hd + 8) = v1;
        if (isL1) {
          u16* sd = seq1 + ((size_t)t * 32 + tid) * 512 + u0;
          *(uint4*)sd = v0; *(uint4*)(sd + 8) = v1;
        }
      }
    }
    // ---- lightweight grid barrier (monotonic flag array) ----
    __syncthreads();
    if (tid == 0) {
      __threadfence();
      __hip_atomic_store(&flags[wg], (u32)(u + 1), __ATOMIC_RELEASE, __HIP_MEMORY_SCOPE_AGENT);
    }
    if (tid < NWG_LSTM) {
      while (__hip_atomic_load(&flags[tid], __ATOMIC_ACQUIRE, __HIP_MEMORY_SCOPE_AGENT) <= (u32)u)
        __builtin_amdgcn_s_sleep(1);
    }
    __syncthreads();
  }
}

// ================= attention: one WG per (b, head, t-tile of 32) =================
__global__ __launch_bounds__(256) void k_attn(const u16* __restrict__ Q,
                                              const u16* __restrict__ Kall,
                                              const u16* __restrict__ Vt,
                                              u16* __restrict__ ctx) {
  __shared__ __align__(16) u16 p_lds[32 * 520];
  __shared__ float red[4][32], red2[4][32], rsum[32];
  const int bid = blockIdx.x;
  const int tt = bid % 5, h = (bid / 5) & 7, b = bid / 40;
  const int tid = threadIdx.x, lane = tid & 63, w = tid >> 6;

  bf16x8 qf[2][2];
  for (int mt = 0; mt < 2; mt++)
    for (int ks = 0; ks < 2; ks++) {
      int t = tt * 32 + mt * 16 + (lane & 15);
      if (t > 128) t = 128;
      qf[mt][ks] = *(const bf16x8*)&Q[((size_t)(b * NH + h) * T1 + t) * HD + ks * 32 + (lane >> 4) * 8];
    }

  f32x4 sc[8][2] = {};
  for (int j = 0; j < 8; j++) {
    int nt = w + 4 * j;
    for (int ks = 0; ks < 2; ks++) {
      int srow = nt * 16 + (lane & 15);
      bf16x8 kf = *(const bf16x8*)&Kall[(size_t)(b * S + srow) * H + h * HD + ks * 32 + (lane >> 4) * 8];
      for (int mt = 0; mt < 2; mt++) sc[j][mt] = MFMA(qf[mt][ks], kf, sc[j][mt]);
    }
  }
  for (int mt = 0; mt < 2; mt++)
    for (int rg = 0; rg < 4; rg++) {
      float m = -1e30f;
      for (int j = 0; j < 8; j++) m = fmaxf(m, sc[j][mt][rg]);
      for (int mk = 1; mk < 16; mk <<= 1) m = fmaxf(m, __shfl_xor(m, mk));
      if ((lane & 15) == 0) red[w][mt * 16 + (lane >> 4) * 4 + rg] = m;
    }
  __syncthreads();
  for (int mt = 0; mt < 2; mt++)
    for (int rg = 0; rg < 4; rg++) {
      int row = mt * 16 + (lane >> 4) * 4 + rg;
      float M = fmaxf(fmaxf(red[0][row], red[1][row]), fmaxf(red[2][row], red[3][row]));
      float s = 0.f;
      for (int j = 0; j < 8; j++) {
        float p = __expf(sc[j][mt][rg] - M);
        s += p;
        p_lds[row * 520 + (w + 4 * j) * 16 + (lane & 15)] = f2bf(p);
      }
      for (int mk = 1; mk < 16; mk <<= 1) s += __shfl_xor(s, mk);
      if ((lane & 15) == 0) red2[w][row] = s;
    }
  __syncthreads();
  if (tid < 32) rsum[tid] = red2[0][tid] + red2[1][tid] + red2[2][tid] + red2[3][tid];

  f32x4 pacc[2] = {};
  {
    int nt = w;
    for (int ks = 0; ks < 16; ks++) {
      bf16x8 vf = *(const bf16x8*)&Vt[((size_t)(b * NH + h) * HD + nt * 16 + (lane & 15)) * S + ks * 32 + (lane >> 4) * 8];
      for (int mt = 0; mt < 2; mt++) {
        bf16x8 pf = *(const bf16x8*)&p_lds[(mt * 16 + (lane & 15)) * 520 + ks * 32 + (lane >> 4) * 8];
        pacc[mt] = MFMA(pf, vf, pacc[mt]);
      }
    }
  }
  __syncthreads();
  for (int mt = 0; mt < 2; mt++)
    for (int rg = 0; rg < 4; rg++) {
      int lrow = mt * 16 + (lane >> 4) * 4 + rg;
      int trow = tt * 32 + lrow;
      if (trow < T1) {
        float v = pacc[mt][rg] / rsum[lrow];
        ctx[((size_t)trow * 32 + b) * H + h * HD + w * 16 + (lane & 15)] = f2bf(v);
      }
    }
}

// ================= in-place log_softmax over V per row =================
__global__ __launch_bounds__(256) void k_lsm(float* __restrict__ out) {
  float* p = out + (size_t)blockIdx.x * VV;
  const int tid = threadIdx.x;
  float m = -1e30f, s = 0.f;
  for (int i = tid; i < VV; i += 256) {
    float v = p[i];
    if (v > m) { s *= __expf(m - v); m = v; }
    s += __expf(v - m);
  }
  for (int off = 32; off; off >>= 1) {
    float m2 = __shfl_xor(m, off), s2 = __shfl_xor(s, off);
    float M = fmaxf(m, m2);
    s = s * __expf(m - M) + s2 * __expf(m2 - M);
    m = M;
  }
  __shared__ float wm[4], ws[4];
  if ((tid & 63) == 0) { wm[tid >> 6] = m; ws[tid >> 6] = s; }
  __syncthreads();
  float M = fmaxf(fmaxf(wm[0], wm[1]), fmaxf(wm[2], wm[3]));
  float Sv = ws[0] * __expf(wm[0] - M) + ws[1] * __expf(wm[1] - M) +
             ws[2] * __expf(wm[2] - M) + ws[3] * __expf(wm[3] - M);
  float lse = M + __logf(Sv);
  for (int i = tid; i < VV; i += 256) p[i] -= lse;
}

// ================= launch =================
extern "C" void kernel_launch(void* const* d_in, const int* in_sizes, int n_in,
                              void* d_out, int out_size, void* d_ws, size_t ws_size,
                              hipStream_t stream) {
  const int* inputs = (const int*)d_in[0];
  const float* enc = (const float*)d_in[1];
  const float* emb = (const float*)d_in[2];
  const float* Wih = (const float*)d_in[3];
  const float* Whh = (const float*)d_in[4];
  const float* bih = (const float*)d_in[5];
  const float* bhh = (const float*)d_in[6];
  const float* ipw = (const float*)d_in[7];
  const float* ipb = (const float*)d_in[8];
  const float* outw = (const float*)d_in[9];
  const float* outb = (const float*)d_in[10];
  const float* projw = (const float*)d_in[11];
  const float* genw = (const float*)d_in[12];
  float* out = (float*)d_out;

  char* wp = (char*)d_ws;
  auto alloc = [&](size_t bytes) {
    char* p = wp;
    wp += (bytes + 255) & ~(size_t)255;
    return p;
  };
  u16* embx = (u16*)alloc((size_t)M_ROWS * E * 2);
  u16* seq1 = (u16*)alloc((size_t)M_ROWS * H * 2);
  u16* WihB = (u16*)alloc((size_t)2 * G4 * E * 2);
  u16* WhhB = (u16*)alloc((size_t)2 * G4 * H * 2);
  u16* ipwB = (u16*)alloc((size_t)3 * H * H * 2);
  u16* outwB = (u16*)alloc((size_t)H * H * 2);
  u16* projwB = (u16*)alloc((size_t)H * H * 2);
  u16* genwB = (u16*)alloc((size_t)VV * H * 2);
  u16* encB = (u16*)alloc((size_t)B * S * H * 2);
  u16* hbuf = (u16*)alloc((size_t)4 * 32 * 512 * 2);
  u32* flags = (u32*)alloc(256);
  float* Gbuf = (float*)alloc((size_t)T1 * G4 * 32 * 4);  // 33.8MB
  u16* Qb = (u16*)alloc((size_t)B * NH * T1 * HD * 2);
  u16* ctxb = (u16*)alloc((size_t)M_ROWS * H * 2);
  // overlays (lifetimes disjoint):
  u16* Kall = (u16*)Gbuf;                                  // after LSTM done
  u16* Vtb = (u16*)((char*)Gbuf + (size_t)B * S * H * 2);
  u16* attout = encB;                                      // enc_bf16 dead after K/V GEMMs
  u16* hidden = (u16*)((char*)encB + (size_t)M_ROWS * H * 2);

  // ---- converts ----
  k_convert<<<1024, 256, 0, stream>>>(Wih, WihB, 2 * G4 * E / 4);
  k_convert<<<1024, 256, 0, stream>>>(Whh, WhhB, 2 * G4 * H / 4);
  k_convert<<<1024, 256, 0, stream>>>(ipw, ipwB, 3 * H * H / 4);
  k_convert<<<1024, 256, 0, stream>>>(outw, outwB, H * H / 4);
  k_convert<<<1024, 256, 0, stream>>>(projw, projwB, H * H / 4);
  k_convert<<<1024, 256, 0, stream>>>(genw, genwB, VV * H / 4);
  k_convert<<<1024, 256, 0, stream>>>(enc, encB, B * S * H / 4);
  k_embed<<<(M_ROWS * (E / 4) + 255) / 256, 256, 0, stream>>>(inputs, emb, embx);
  hipMemsetAsync(flags, 0, 256, stream);

  // ---- gate precompute for layer 0 only ----
  k_gemm<0><<<dim3(16, 33), 256, 0, stream>>>(embx, WihB, bih, bhh, Gbuf, M_ROWS, G4, 1.f);

  // ---- fused pipelined 2-layer LSTM ----
  {
    const float* g0 = Gbuf;
    const u16* wh0 = WhhB;
    const u16* wi1 = WihB + (size_t)G4 * E;
    const u16* wh1 = WhhB + (size_t)G4 * H;
    const float* b1i = bih + G4;
    const float* b1h = bhh + G4;
    u16* sq = seq1; u16* hb = hbuf; u32* fl = flags;
    void* args[] = {&g0, &wh0, &wi1, &wh1, &b1i, &b1h, &sq, &hb, &fl};
    hipLaunchCooperativeKernel((void*)k_lstm2, dim3(NWG_LSTM), dim3(256), args, 0, stream);
  }

  // ---- attention projections (K/V overlay Gbuf — LSTM finished) ----
  k_gemm<1><<<dim3(4, 128), 256, 0, stream>>>(encB, ipwB + (size_t)H * H, ipb + H, nullptr,
                                              Kall, B * S, H, 1.f);
  k_gemm<3><<<dim3(4, 128), 256, 0, stream>>>(encB, ipwB + (size_t)2 * H * H, ipb + 2 * H, nullptr,
                                              Vtb, B * S, H, 1.f);
  k_gemm<2><<<dim3(4, 33), 256, 0, stream>>>(seq1, ipwB, ipb, nullptr, Qb, M_ROWS, H, 0.125f);

  k_attn<<<B * NH * 5, 256, 0, stream>>>(Qb, Kall, Vtb, ctxb);

  // ---- output projections ----
  k_gemm<1><<<dim3(4, 33), 256, 0, stream>>>(ctxb, outwB, outb, nullptr, attout, M_ROWS, H, 1.f);
  k_gemm<1><<<dim3(4, 33), 256, 0, stream>>>(attout, projwB, nullptr, nullptr, hidden, M_ROWS, H, 1.f);
  k_gemm<4><<<dim3(79, 33), 256, 0, stream>>>(hidden, genwB, nullptr, nullptr, out, M_ROWS, VV, 1.f);

  k_lsm<<<M_ROWS, 256, 0, stream>>>(out);

  (void)in_sizes; (void)n_in; (void)out_size; (void)ws_size;
}

// Round 3
// 1979.578 us; speedup vs baseline: 1.7238x; 1.0455x over previous
//
#include <hip/hip_runtime.h>
#include <cstdint>

typedef unsigned short u16;
typedef unsigned int u32;
typedef __attribute__((ext_vector_type(8))) short bf16x8;
typedef __attribute__((ext_vector_type(4))) float f32x4;

#define DI __device__ __forceinline__

// ---- problem constants ----
constexpr int VV = 10000, E = 512, H = 512, NH = 8, HD = 64;
constexpr int B = 32, T = 128, S = 512, T1 = 129;
constexpr int G4 = 2048;          // 4*H
constexpr int M_ROWS = T1 * B;    // 4128
constexpr int NWG_LSTM = 64;      // 32 for layer0 + 32 for layer1

DI u16 f2bf(float f) {
  uint32_t u = __builtin_bit_cast(uint32_t, f);
  u = (u + 0x7FFF + ((u >> 16) & 1)) >> 16;
  return (u16)u;
}
DI float sigm(float x) { return 1.f / (1.f + __expf(-x)); }
DI float tanh_(float x) { return 1.f - 2.f / (__expf(2.f * x) + 1.f); }  // NaN-free form

DI f32x4 MFMA(bf16x8 a, bf16x8 b, f32x4 c) {
  return __builtin_amdgcn_mfma_f32_16x16x32_bf16(a, b, c, 0, 0, 0);
}

// relaxed agent-scope atomics: sc1 read/write-through at coherence point,
// NO L2 invalidate/writeback (the round-2 acquire/release killer).
DI u32 aload(const u32* p) {
  return __hip_atomic_load((u32*)p, __ATOMIC_RELAXED, __HIP_MEMORY_SCOPE_AGENT);
}
DI void astore(u32* p, u32 v) {
  __hip_atomic_store(p, v, __ATOMIC_RELAXED, __HIP_MEMORY_SCOPE_AGENT);
}

#define GLD_LDS(gptr, lptr)                                                     \
  __builtin_amdgcn_global_load_lds(                                             \
      (const __attribute__((address_space(1))) uint32_t*)(const void*)(gptr),   \
      (__attribute__((address_space(3))) uint32_t*)(void*)(lptr), 16, 0, 0)

// ================= fused convert f32 -> bf16 for all weight tensors =================
struct CJobs {
  const float* s[7];
  u16* d[7];
  int n4[7];
  int tot;
};
__global__ __launch_bounds__(256) void k_convert_all(CJobs j) {
  int i = blockIdx.x * 256 + threadIdx.x;
  int stride = gridDim.x * 256;
  for (; i < j.tot; i += stride) {
    int rem = i, k = 0;
    while (rem >= j.n4[k]) { rem -= j.n4[k]; k++; }
    float4 v = ((const float4*)j.s[k])[rem];
    ushort4 o;
    o.x = f2bf(v.x); o.y = f2bf(v.y); o.z = f2bf(v.z); o.w = f2bf(v.w);
    ((ushort4*)j.d[k])[rem] = o;
  }
}

// ================= embedding gather (+SOS prepend) -> bf16 [T1][B][E] =================
__global__ __launch_bounds__(256) void k_embed(const int* __restrict__ toks,
                                               const float* __restrict__ emb,
                                               u16* __restrict__ out) {
  int idx = blockIdx.x * 256 + threadIdx.x;  // one float4 chunk
  int total = T1 * B * (E / 4);
  if (idx >= total) return;
  int ch = idx & (E / 4 - 1);
  int r = idx / (E / 4);
  int t = r >> 5, b = r & 31;
  int tok = (t == 0) ? 1 : toks[b * T + (t - 1)];
  float4 v = ((const float4*)(emb + (size_t)tok * E))[ch];
  ushort4 o;
  o.x = f2bf(v.x); o.y = f2bf(v.y); o.z = f2bf(v.z); o.w = f2bf(v.w);
  ((ushort4*)out)[idx] = o;
}

// ================= generic NT GEMM, bf16 in, fp32 acc =================
// C[r][c] = sum_k A[r][k]*Bm[c][k],  K == 512 fixed.
// MODE 0: fp32 gate layout [T1][2048][B] + bias + bias2
// MODE 1: bf16 [M][N] (+bias optional)
// MODE 2: Q layout bf16 [B][NH][T1][HD], (v+bias)*scale
// MODE 3: Vt layout bf16 [B][NH][HD][S], v+bias
// MODE 4: logits fp32, row remap (t,b)->(b,t): d_out[(b*129+t)*10000 + c]
template <int MODE>
__global__ __launch_bounds__(256) void k_gemm(const u16* __restrict__ A,
                                              const u16* __restrict__ Bm,
                                              const float* __restrict__ bias,
                                              const float* __restrict__ bias2,
                                              void* __restrict__ Cout, int M, int N,
                                              float scale) {
  __shared__ __align__(16) u16 As[128 * 64];
  __shared__ __align__(16) u16 Bs[128 * 64];
  const int tid = threadIdx.x, lane = tid & 63, wid = tid >> 6;
  const int wm = wid >> 1, wn = wid & 1;
  const int r0 = blockIdx.y * 128, n0 = blockIdx.x * 128;
  f32x4 acc[4][4] = {};
  const int brow = wid * 32;  // this wave stages rows [brow, brow+32) of both tiles

  for (int k0 = 0; k0 < 512; k0 += 64) {
    for (int q = 0; q < 4; q++) {
      int row_l = brow + q * 8 + (lane >> 3);
      int slot = lane & 7;
      int scol = (slot ^ (row_l & 7)) * 8;  // pre-swizzled source (rule #21)
      int ra = r0 + row_l; if (ra > M - 1) ra = M - 1;
      GLD_LDS(A + (size_t)ra * 512 + k0 + scol, &As[(brow + q * 8) * 64]);
      int rb = n0 + row_l; if (rb > N - 1) rb = N - 1;
      GLD_LDS(Bm + (size_t)rb * 512 + k0 + scol, &Bs[(brow + q * 8) * 64]);
    }
    __syncthreads();
    for (int ks = 0; ks < 2; ks++) {
      bf16x8 af[4], bf[4];
      for (int mt = 0; mt < 4; mt++) {
        int row = wm * 64 + mt * 16 + (lane & 15);
        int slot = (ks * 4 + (lane >> 4)) ^ (row & 7);
        af[mt] = *(const bf16x8*)&As[row * 64 + slot * 8];
      }
      for (int nt = 0; nt < 4; nt++) {
        int row = wn * 64 + nt * 16 + (lane & 15);
        int slot = (ks * 4 + (lane >> 4)) ^ (row & 7);
        bf[nt] = *(const bf16x8*)&Bs[row * 64 + slot * 8];
      }
      for (int mt = 0; mt < 4; mt++)
        for (int nt = 0; nt < 4; nt++)
          acc[mt][nt] = MFMA(af[mt], bf[nt], acc[mt][nt]);
    }
    __syncthreads();
  }

  for (int mt = 0; mt < 4; mt++)
    for (int nt = 0; nt < 4; nt++) {
      int c = n0 + wn * 64 + nt * 16 + (lane & 15);
      float bv = 0.f;
      if (c < N) {
        if (bias) bv += bias[c];
        if (bias2) bv += bias2[c];
      }
      for (int rg = 0; rg < 4; rg++) {
        int r = r0 + wm * 64 + mt * 16 + (lane >> 4) * 4 + rg;
        if (r >= M || c >= N) continue;
        float v = acc[mt][nt][rg];
        if constexpr (MODE == 0) {
          int t = r >> 5, b = r & 31;
          ((float*)Cout)[((size_t)t * G4 + c) * 32 + b] = v + bv;
        } else if constexpr (MODE == 1) {
          ((u16*)Cout)[(size_t)r * N + c] = f2bf(v + bv);
        } else if constexpr (MODE == 2) {
          int t = r >> 5, b = r & 31, h = c >> 6, d = c & 63;
          ((u16*)Cout)[((size_t)(b * NH + h) * T1 + t) * HD + d] = f2bf((v + bv) * scale);
        } else if constexpr (MODE == 3) {
          int b = r >> 9, s = r & 511, h = c >> 6, d = c & 63;
          ((u16*)Cout)[((size_t)(b * NH + h) * HD + d) * S + s] = f2bf(v + bv);
        } else {
          int t = r >> 5, b = r & 31;
          ((float*)Cout)[((size_t)b * T1 + t) * VV + c] = v;
        }
      }
    }
}

// ================= fused 2-layer pipelined LSTM (cooperative, relaxed-atomic sync) ==
// WG 0..31  = layer0 unit-slice wg*16,   reads precomputed G0 [T1][2048][32] fp32
// WG 32..63 = layer1 unit-slice (wg-32)*16, computes x-gates Wih1*h0 on the fly
// hbuf: [2][2][32][512] bf16 : hb0 ping-pong then hb1 ping-pong
// All cross-WG data moves via agent-relaxed (sc1) dword atomics -> no L2 flush/inval.
__global__ __launch_bounds__(256) void k_lstm2(const float* __restrict__ G0,
                                               const u16* __restrict__ Whh0,
                                               const u16* __restrict__ Wih1,
                                               const u16* __restrict__ Whh1,
                                               const float* __restrict__ bih1,
                                               const float* __restrict__ bhh1,
                                               u16* __restrict__ seq1,
                                               u16* __restrict__ hbuf,
                                               u32* __restrict__ flags) {
  __shared__ __align__(16) u16 hA[32 * 512];   // recurrent h tile (overlaid by xchg/hx after MFMA)
  __shared__ __align__(16) u16 hX[32 * 512];   // L1 only: x = h0[u-1]
  float* xchg = (float*)hA;                    // [4][32][17] = 8704 B (after-MFMA overlay)
  u16* hx = (u16*)hA + 4352;                   // 1 KB transpose staging @ byte 8704
  const int tid = threadIdx.x, lane = tid & 63, g = tid >> 6;
  const int wg = blockIdx.x;
  const bool isL1 = wg >= 32;
  const int u0 = (isL1 ? wg - 32 : wg) * 16;

  u16* hb0 = hbuf;                  // [2][32][512]
  u16* hb1 = hbuf + 2 * 32 * 512;   // [2][32][512]

  // persistent weight fragments (A-operand), 64 VGPR each set
  bf16x8 afh[16], afx[16];
  {
    const u16* Wh = isL1 ? Whh1 : Whh0;
    int row = g * 512 + u0 + (lane & 15);
    const u16* wp = Wh + (size_t)row * 512 + (lane >> 4) * 8;
    for (int ks = 0; ks < 16; ks++) afh[ks] = *(const bf16x8*)(wp + ks * 32);
    if (isL1) {
      const u16* xp = Wih1 + (size_t)row * 512 + (lane >> 4) * 8;
      for (int ks = 0; ks < 16; ks++) afx[ks] = *(const bf16x8*)(xp + ks * 32);
    }
  }
  // L1 per-thread gate biases (bih1+bhh1) for its 2 (b,u)-points
  float bsum[2][4];
  if (isL1) {
    for (int j = 0; j < 2; j++) {
      int uu = (tid + 256 * j) >> 5;
      for (int gg = 0; gg < 4; gg++)
        bsum[j][gg] = bih1[gg * 512 + u0 + uu] + bhh1[gg * 512 + u0 + uu];
    }
  }
  float cst[2] = {0.f, 0.f};

  for (int u = 0; u < 130; u++) {
    const int t = isL1 ? (u - 1) : u;
    const bool active = isL1 ? (u >= 1) : (u < 129);

    if (active) {
      float gpre[2][4];
      if (!isL1) {
        // prefetch this step's G0 into regs (overlaps with h-stage latency)
        for (int j = 0; j < 2; j++) {
          int p = tid + 256 * j; int b = p & 31, uu = p >> 5;
          const float* Gp = G0 + ((size_t)t * G4 + u0 + uu) * 32 + b;
          gpre[j][0] = Gp[0];         gpre[j][1] = Gp[512 * 32];
          gpre[j][2] = Gp[1024 * 32]; gpre[j][3] = Gp[1536 * 32];
        }
      }
      // ---- issue all cross-WG h loads (sc1, pipelined), then write LDS swizzled ----
      u32 va[8][4], vx[8][4];
      const u16* srcA = isL1 ? (hb1 + (size_t)(t & 1) * (32 * 512))
                             : (hb0 + (size_t)(t & 1) * (32 * 512));
      const u16* srcX = hb0 + (size_t)(u & 1) * (32 * 512);  // h0[u-1]
      if (t > 0) {
        for (int j = 0; j < 8; j++) {
          int cid = tid + 256 * j;
          const u32* ps = (const u32*)(srcA + (cid >> 6) * 512 + (cid & 63) * 8);
          for (int q = 0; q < 4; q++) va[j][q] = aload(ps + q);
        }
      }
      if (isL1) {
        for (int j = 0; j < 8; j++) {
          int cid = tid + 256 * j;
          const u32* ps = (const u32*)(srcX + (cid >> 6) * 512 + (cid & 63) * 8);
          for (int q = 0; q < 4; q++) vx[j][q] = aload(ps + q);
        }
      }
      for (int j = 0; j < 8; j++) {
        int cid = tid + 256 * j;
        int row = cid >> 6, slot = cid & 63;
        int dsto = row * 512 + ((slot ^ (row & 7)) * 8);
        uint4 w;
        if (t == 0) { w.x = 0; w.y = 0; w.z = 0; w.w = 0; }
        else { w.x = va[j][0]; w.y = va[j][1]; w.z = va[j][2]; w.w = va[j][3]; }
        *(uint4*)&hA[dsto] = w;
        if (isL1) {
          uint4 x; x.x = vx[j][0]; x.y = vx[j][1]; x.z = vx[j][2]; x.w = vx[j][3];
          *(uint4*)&hX[dsto] = x;
        }
      }
      __syncthreads();
      // ---- recurrent (+x) dots: wave g = gate g, 16 units x 32 batches ----
      f32x4 acc[2] = {};
      for (int ks = 0; ks < 16; ks++)
        for (int nt = 0; nt < 2; nt++) {
          int row = nt * 16 + (lane & 15);
          int off = row * 512 + (((ks * 4 + (lane >> 4)) ^ (row & 7)) * 8);
          acc[nt] = MFMA(afh[ks], *(const bf16x8*)&hA[off], acc[nt]);
          if (isL1) acc[nt] = MFMA(afx[ks], *(const bf16x8*)&hX[off], acc[nt]);
        }
      __syncthreads();  // all MFMA reads of hA done before xchg overlays it
      for (int nt = 0; nt < 2; nt++)
        for (int rg = 0; rg < 4; rg++)
          xchg[(g * 32 + nt * 16 + (lane & 15)) * 17 + (lane >> 4) * 4 + rg] = acc[nt][rg];
      __syncthreads();
      // ---- combine gates, update c (registers), produce h ----
      for (int j = 0; j < 2; j++) {
        int p = tid + 256 * j; int b = p & 31, uu = p >> 5;
        float gi, gf, gg_, go;
        if (!isL1) { gi = gpre[j][0]; gf = gpre[j][1]; gg_ = gpre[j][2]; go = gpre[j][3]; }
        else       { gi = bsum[j][0]; gf = bsum[j][1]; gg_ = bsum[j][2]; go = bsum[j][3]; }
        float i_ = sigm(xchg[(0 * 32 + b) * 17 + uu] + gi);
        float f_ = sigm(xchg[(1 * 32 + b) * 17 + uu] + gf);
        float g_ = tanh_(xchg[(2 * 32 + b) * 17 + uu] + gg_);
        float o_ = sigm(xchg[(3 * 32 + b) * 17 + uu] + go);
        float c = f_ * cst[j] + i_ * g_;
        cst[j] = c;
        hx[b * 16 + uu] = f2bf(o_ * tanh_(c));
      }
      __syncthreads();
      // ---- publish h via sc1 dword stores (visible at coherence point, no flush) ----
      if (tid < 32) {
        const u32* hs = (const u32*)&hx[tid * 16];
        u16* hd = (isL1 ? hb1 : hb0) + (size_t)((t + 1) & 1) * (32 * 512) +
                  (size_t)tid * 512 + u0;
        u32* hd32 = (u32*)hd;
        for (int q = 0; q < 8; q++) astore(hd32 + q, hs[q]);
        if (isL1) {
          u16* sd = seq1 + ((size_t)t * 32 + tid) * 512 + u0;
          *(uint4*)sd = *(const uint4*)&hx[tid * 16];
          *(uint4*)(sd + 8) = *(const uint4*)&hx[tid * 16 + 8];
        }
      }
    }
    // ---- flag + poll (all relaxed; one vmcnt drain orders publish before flag) ----
    asm volatile("s_waitcnt vmcnt(0)" ::: "memory");
    if (tid == 0) astore(&flags[wg], (u32)(u + 1));
    if (tid < NWG_LSTM) {
      while (aload(&flags[tid]) <= (u32)u) __builtin_amdgcn_s_sleep(2);
    }
    __syncthreads();
  }
}

// ================= attention: one WG per (b, head, t-tile of 32) =================
__global__ __launch_bounds__(256) void k_attn(const u16* __restrict__ Q,
                                              const u16* __restrict__ Kall,
                                              const u16* __restrict__ Vt,
                                              u16* __restrict__ ctx) {
  __shared__ __align__(16) u16 p_lds[32 * 520];
  __shared__ float red[4][32], red2[4][32], rsum[32];
  const int bid = blockIdx.x;
  const int tt = bid % 5, h = (bid / 5) & 7, b = bid / 40;
  const int tid = threadIdx.x, lane = tid & 63, w = tid >> 6;

  bf16x8 qf[2][2];
  for (int mt = 0; mt < 2; mt++)
    for (int ks = 0; ks < 2; ks++) {
      int t = tt * 32 + mt * 16 + (lane & 15);
      if (t > 128) t = 128;
      qf[mt][ks] = *(const bf16x8*)&Q[((size_t)(b * NH + h) * T1 + t) * HD + ks * 32 + (lane >> 4) * 8];
    }

  f32x4 sc[8][2] = {};
  for (int j = 0; j < 8; j++) {
    int nt = w + 4 * j;
    for (int ks = 0; ks < 2; ks++) {
      int srow = nt * 16 + (lane & 15);
      bf16x8 kf = *(const bf16x8*)&Kall[(size_t)(b * S + srow) * H + h * HD + ks * 32 + (lane >> 4) * 8];
      for (int mt = 0; mt < 2; mt++) sc[j][mt] = MFMA(qf[mt][ks], kf, sc[j][mt]);
    }
  }
  for (int mt = 0; mt < 2; mt++)
    for (int rg = 0; rg < 4; rg++) {
      float m = -1e30f;
      for (int j = 0; j < 8; j++) m = fmaxf(m, sc[j][mt][rg]);
      for (int mk = 1; mk < 16; mk <<= 1) m = fmaxf(m, __shfl_xor(m, mk));
      if ((lane & 15) == 0) red[w][mt * 16 + (lane >> 4) * 4 + rg] = m;
    }
  __syncthreads();
  for (int mt = 0; mt < 2; mt++)
    for (int rg = 0; rg < 4; rg++) {
      int row = mt * 16 + (lane >> 4) * 4 + rg;
      float M = fmaxf(fmaxf(red[0][row], red[1][row]), fmaxf(red[2][row], red[3][row]));
      float s = 0.f;
      for (int j = 0; j < 8; j++) {
        float p = __expf(sc[j][mt][rg] - M);
        s += p;
        p_lds[row * 520 + (w + 4 * j) * 16 + (lane & 15)] = f2bf(p);
      }
      for (int mk = 1; mk < 16; mk <<= 1) s += __shfl_xor(s, mk);
      if ((lane & 15) == 0) red2[w][row] = s;
    }
  __syncthreads();
  if (tid < 32) rsum[tid] = red2[0][tid] + red2[1][tid] + red2[2][tid] + red2[3][tid];

  f32x4 pacc[2] = {};
  {
    int nt = w;
    for (int ks = 0; ks < 16; ks++) {
      bf16x8 vf = *(const bf16x8*)&Vt[((size_t)(b * NH + h) * HD + nt * 16 + (lane & 15)) * S + ks * 32 + (lane >> 4) * 8];
      for (int mt = 0; mt < 2; mt++) {
        bf16x8 pf = *(const bf16x8*)&p_lds[(mt * 16 + (lane & 15)) * 520 + ks * 32 + (lane >> 4) * 8];
        pacc[mt] = MFMA(pf, vf, pacc[mt]);
      }
    }
  }
  __syncthreads();
  for (int mt = 0; mt < 2; mt++)
    for (int rg = 0; rg < 4; rg++) {
      int lrow = mt * 16 + (lane >> 4) * 4 + rg;
      int trow = tt * 32 + lrow;
      if (trow < T1) {
        float v = pacc[mt][rg] / rsum[lrow];
        ctx[((size_t)trow * 32 + b) * H + h * HD + w * 16 + (lane & 15)] = f2bf(v);
      }
    }
}

// ================= in-place log_softmax over V per row =================
__global__ __launch_bounds__(256) void k_lsm(float* __restrict__ out) {
  float* p = out + (size_t)blockIdx.x * VV;
  const int tid = threadIdx.x;
  float m = -1e30f, s = 0.f;
  for (int i = tid; i < VV; i += 256) {
    float v = p[i];
    if (v > m) { s *= __expf(m - v); m = v; }
    s += __expf(v - m);
  }
  for (int off = 32; off; off >>= 1) {
    float m2 = __shfl_xor(m, off), s2 = __shfl_xor(s, off);
    float M = fmaxf(m, m2);
    s = s * __expf(m - M) + s2 * __expf(m2 - M);
    m = M;
  }
  __shared__ float wm[4], ws[4];
  if ((tid & 63) == 0) { wm[tid >> 6] = m; ws[tid >> 6] = s; }
  __syncthreads();
  float M = fmaxf(fmaxf(wm[0], wm[1]), fmaxf(wm[2], wm[3]));
  float Sv = ws[0] * __expf(wm[0] - M) + ws[1] * __expf(wm[1] - M) +
             ws[2] * __expf(wm[2] - M) + ws[3] * __expf(wm[3] - M);
  float lse = M + __logf(Sv);
  for (int i = tid; i < VV; i += 256) p[i] -= lse;
}

// ================= launch =================
extern "C" void kernel_launch(void* const* d_in, const int* in_sizes, int n_in,
                              void* d_out, int out_size, void* d_ws, size_t ws_size,
                              hipStream_t stream) {
  const int* inputs = (const int*)d_in[0];
  const float* enc = (const float*)d_in[1];
  const float* emb = (const float*)d_in[2];
  const float* Wih = (const float*)d_in[3];
  const float* Whh = (const float*)d_in[4];
  const float* bih = (const float*)d_in[5];
  const float* bhh = (const float*)d_in[6];
  const float* ipw = (const float*)d_in[7];
  const float* ipb = (const float*)d_in[8];
  const float* outw = (const float*)d_in[9];
  const float* outb = (const float*)d_in[10];
  const float* projw = (const float*)d_in[11];
  const float* genw = (const float*)d_in[12];
  float* out = (float*)d_out;

  char* wp = (char*)d_ws;
  auto alloc = [&](size_t bytes) {
    char* p = wp;
    wp += (bytes + 255) & ~(size_t)255;
    return p;
  };
  u16* embx = (u16*)alloc((size_t)M_ROWS * E * 2);
  u16* seq1 = (u16*)alloc((size_t)M_ROWS * H * 2);
  u16* WihB = (u16*)alloc((size_t)2 * G4 * E * 2);
  u16* WhhB = (u16*)alloc((size_t)2 * G4 * H * 2);
  u16* ipwB = (u16*)alloc((size_t)3 * H * H * 2);
  u16* outwB = (u16*)alloc((size_t)H * H * 2);
  u16* projwB = (u16*)alloc((size_t)H * H * 2);
  u16* genwB = (u16*)alloc((size_t)VV * H * 2);
  u16* encB = (u16*)alloc((size_t)B * S * H * 2);
  u16* hbuf = (u16*)alloc((size_t)4 * 32 * 512 * 2);
  u32* flags = (u32*)alloc(256);
  float* Gbuf = (float*)alloc((size_t)T1 * G4 * 32 * 4);  // 33.8MB
  u16* Qb = (u16*)alloc((size_t)B * NH * T1 * HD * 2);
  u16* ctxb = (u16*)alloc((size_t)M_ROWS * H * 2);
  // overlays (lifetimes disjoint):
  u16* Kall = (u16*)Gbuf;                                  // after LSTM done
  u16* Vtb = (u16*)((char*)Gbuf + (size_t)B * S * H * 2);
  u16* attout = encB;                                      // enc_bf16 dead after K/V GEMMs
  u16* hidden = (u16*)((char*)encB + (size_t)M_ROWS * H * 2);

  // ---- converts (single fused launch) ----
  {
    CJobs cj;
    cj.s[0] = Wih;  cj.d[0] = WihB;  cj.n4[0] = 2 * G4 * E / 4;
    cj.s[1] = Whh;  cj.d[1] = WhhB;  cj.n4[1] = 2 * G4 * H / 4;
    cj.s[2] = ipw;  cj.d[2] = ipwB;  cj.n4[2] = 3 * H * H / 4;
    cj.s[3] = outw; cj.d[3] = outwB; cj.n4[3] = H * H / 4;
    cj.s[4] = projw; cj.d[4] = projwB; cj.n4[4] = H * H / 4;
    cj.s[5] = genw; cj.d[5] = genwB; cj.n4[5] = VV * H / 4;
    cj.s[6] = enc;  cj.d[6] = encB;  cj.n4[6] = B * S * H / 4;
    cj.tot = 0;
    for (int k = 0; k < 7; k++) cj.tot += cj.n4[k];
    k_convert_all<<<1024, 256, 0, stream>>>(cj);
  }
  k_embed<<<(M_ROWS * (E / 4) + 255) / 256, 256, 0, stream>>>(inputs, emb, embx);
  hipMemsetAsync(flags, 0, 256, stream);

  // ---- gate precompute for layer 0 only ----
  k_gemm<0><<<dim3(16, 33), 256, 0, stream>>>(embx, WihB, bih, bhh, Gbuf, M_ROWS, G4, 1.f);

  // ---- fused pipelined 2-layer LSTM ----
  {
    const float* g0 = Gbuf;
    const u16* wh0 = WhhB;
    const u16* wi1 = WihB + (size_t)G4 * E;
    const u16* wh1 = WhhB + (size_t)G4 * H;
    const float* b1i = bih + G4;
    const float* b1h = bhh + G4;
    u16* sq = seq1; u16* hb = hbuf; u32* fl = flags;
    void* args[] = {&g0, &wh0, &wi1, &wh1, &b1i, &b1h, &sq, &hb, &fl};
    hipLaunchCooperativeKernel((void*)k_lstm2, dim3(NWG_LSTM), dim3(256), args, 0, stream);
  }

  // ---- attention projections (K/V overlay Gbuf — LSTM finished) ----
  k_gemm<1><<<dim3(4, 128), 256, 0, stream>>>(encB, ipwB + (size_t)H * H, ipb + H, nullptr,
                                              Kall, B * S, H, 1.f);
  k_gemm<3><<<dim3(4, 128), 256, 0, stream>>>(encB, ipwB + (size_t)2 * H * H, ipb + 2 * H, nullptr,
                                              Vtb, B * S, H, 1.f);
  k_gemm<2><<<dim3(4, 33), 256, 0, stream>>>(seq1, ipwB, ipb, nullptr, Qb, M_ROWS, H, 0.125f);

  k_attn<<<B * NH * 5, 256, 0, stream>>>(Qb, Kall, Vtb, ctxb);

  // ---- output projections ----
  k_gemm<1><<<dim3(4, 33), 256, 0, stream>>>(ctxb, outwB, outb, nullptr, attout, M_ROWS, H, 1.f);
  k_gemm<1><<<dim3(4, 33), 256, 0, stream>>>(attout, projwB, nullptr, nullptr, hidden, M_ROWS, H, 1.f);
  k_gemm<4><<<dim3(79, 33), 256, 0, stream>>>(hidden, genwB, nullptr, nullptr, out, M_ROWS, VV, 1.f);

  k_lsm<<<M_ROWS, 256, 0, stream>>>(out);

  (void)in_sizes; (void)n_in; (void)out_size; (void)ws_size;
}